// Round 3
// baseline (912.432 us; speedup 1.0000x reference)
//
#include <hip/hip_runtime.h>

#define NB   4
#define CIN  64
#define COUT 64
#define HH   160
#define WW   160
#define HW   (HH * WW)

// ---------------------------------------------------------------------------
// Pre-pass: transpose weight [O][C][3][3] -> wt[t][c][o]  (t = ky*3+kx)
// so the main kernel reads consecutive o's at a wave-uniform address
// (compiler scalarizes -> s_load, inner loop becomes v_fmac v, s, v).
// ---------------------------------------------------------------------------
__global__ void wt_transpose_kernel(const float* __restrict__ w,
                                    float* __restrict__ wt) {
    int i = blockIdx.x * 256 + threadIdx.x;       // i = (t*64 + c)*64 + o
    if (i < 9 * CIN * COUT) {
        int o = i & 63;
        int c = (i >> 6) & 63;
        int t = i >> 12;
        wt[i] = w[(o * CIN + c) * 9 + t];
    }
}

// ---------------------------------------------------------------------------
// Main kernel: 256 threads (4 waves) per 64 consecutive output pixels.
// lane = pixel (same 64 pixels for all 4 waves); wave w computes output
// channels [16w, 16w+16) over ALL input channels -> acc[16] in registers,
// no LDS reduction, no dynamic register indexing (round-2 lesson: runtime-
// indexed acc[] -> scratch -> 732 MB of spill writes).
// t-outer / c-inner: geometry once per tap; the 4 waves gather the same
// ~2.4 KB/channel region -> L1-broadcast. Weights wave-uniform -> s_load.
// ---------------------------------------------------------------------------
__global__ __launch_bounds__(256) void pdconv_kernel(
    const float* __restrict__ in,        // [B][CIN][H][W]
    const float* __restrict__ wt,        // [9][CIN][COUT]
    const float* __restrict__ rate_map,  // [B][1][H][W]
    const float* __restrict__ bias,      // [COUT]
    float* __restrict__ out)             // [B][COUT][H][W]
{
    const int tid  = threadIdx.x;
    const int lane = tid & 63;
    const int wave = tid >> 6;

    // XCD-bijective swizzle: 1600 blocks, 1600 % 8 == 0. Consecutive
    // original IDs round-robin XCDs; remap so each XCD gets a contiguous
    // band of pixel-strips (vertical halo reuse in its private L2).
    const int cpx = gridDim.x >> 3;                       // 200
    const int bid = (blockIdx.x & 7) * cpx + (blockIdx.x >> 3);

    const int p    = bid * 64 + lane;       // flat pixel over (b,y,x)
    const int b    = p / HW;                // 25600 % 64 == 0: wave in one image
    const int pix  = p - b * HW;
    const int y    = pix / WW;
    const int x    = pix - y * WW;

    const float rate = rate_map[p];
    const float fy = (float)y, fx = (float)x;

    float acc[16];
#pragma unroll
    for (int j = 0; j < 16; ++j) acc[j] = 0.0f;

    const int oc0 = wave * 16;                            // this wave's outputs
    const float* img = in + (size_t)b * CIN * HW;

#pragma unroll 1
    for (int t = 0; t < 9; ++t) {
        const int ky = t / 3;
        const int kx = t - 3 * ky;

        const float sy  = fy + (float)(ky - 1) * rate;
        const float sx  = fx + (float)(kx - 1) * rate;
        const float y0f = floorf(sy), x0f = floorf(sx);
        const float wy  = sy - y0f,   wx  = sx - x0f;
        const int   y0  = (int)y0f,   x0  = (int)x0f;
        const int   y1  = y0 + 1,     x1  = x0 + 1;

        const float omwy = 1.0f - wy, omwx = 1.0f - wx;
        const float vy0 = (y0 >= 0 && y0 < HH) ? 1.0f : 0.0f;
        const float vy1 = (y1 >= 0 && y1 < HH) ? 1.0f : 0.0f;
        const float vx0 = (x0 >= 0 && x0 < WW) ? 1.0f : 0.0f;
        const float vx1 = (x1 >= 0 && x1 < WW) ? 1.0f : 0.0f;

        const float c00 = omwy * omwx * vy0 * vx0;
        const float c01 = omwy * wx   * vy0 * vx1;
        const float c10 = wy   * omwx * vy1 * vx0;
        const float c11 = wy   * wx   * vy1 * vx1;

        const int cy0 = min(max(y0, 0), HH - 1);
        const int cy1 = min(max(y1, 0), HH - 1);
        const int cx0 = min(max(x0, 0), WW - 1);
        const int cx1 = min(max(x1, 0), WW - 1);

        const int i00 = cy0 * WW + cx0;
        const int i01 = cy0 * WW + cx1;
        const int i10 = cy1 * WW + cx0;
        const int i11 = cy1 * WW + cx1;

        const float* wr0 = wt + t * (CIN * COUT) + oc0;   // + c*COUT per c

        // software-pipelined over c: gathers for c+1 issue before c's fmacs
        float v00 = img[i00], v01 = img[i01], v10 = img[i10], v11 = img[i11];
#pragma unroll 1
        for (int c = 0; c < CIN - 1; ++c) {
            const float a = c00 * v00 + c01 * v01 + c10 * v10 + c11 * v11;
            const float* nxt = img + (size_t)(c + 1) * HW;
            v00 = nxt[i00]; v01 = nxt[i01]; v10 = nxt[i10]; v11 = nxt[i11];
            const float* wr = wr0 + c * COUT;             // wave-uniform -> s_load
#pragma unroll
            for (int j = 0; j < 16; ++j)
                acc[j] = fmaf(wr[j], a, acc[j]);
        }
        {   // epilogue c = CIN-1
            const float a = c00 * v00 + c01 * v01 + c10 * v10 + c11 * v11;
            const float* wr = wr0 + (CIN - 1) * COUT;
#pragma unroll
            for (int j = 0; j < 16; ++j)
                acc[j] = fmaf(wr[j], a, acc[j]);
        }
    }

    float* op = out + (size_t)b * COUT * HW + pix;
#pragma unroll
    for (int j = 0; j < 16; ++j)
        op[(size_t)(oc0 + j) * HW] = acc[j] + bias[oc0 + j];
}

extern "C" void kernel_launch(void* const* d_in, const int* in_sizes, int n_in,
                              void* d_out, int out_size, void* d_ws, size_t ws_size,
                              hipStream_t stream) {
    (void)in_sizes; (void)n_in; (void)out_size; (void)ws_size;
    const float* in   = (const float*)d_in[0];
    const float* w    = (const float*)d_in[1];
    const float* rm   = (const float*)d_in[2];
    const float* bias = (const float*)d_in[3];
    float* out = (float*)d_out;
    float* wtb = (float*)d_ws;   // 147,456 B scratch for transposed weight

    hipLaunchKernelGGL(wt_transpose_kernel, dim3(144), dim3(256), 0, stream, w, wtb);

    const int nblocks = (NB * HW) / 64;  // 1600
    hipLaunchKernelGGL(pdconv_kernel, dim3(nblocks), dim3(256), 0, stream,
                       in, wtb, rm, bias, out);
}

// Round 6
// 190.841 us; speedup vs baseline: 4.7811x; 4.7811x over previous
//
#include <hip/hip_runtime.h>

#define NB   4
#define CIN  64
#define COUT 64
#define HH   160
#define WW   160
#define HW   (HH * WW)

// ---------------------------------------------------------------------------
// Pre-pass: transpose weight [O][C][3][3] -> wt[t][c][o]  (t = ky*3+kx)
// so the weight row for a (t,c) pair is 64 consecutive floats at a
// wave-uniform address -> s_load into SGPRs.
// ---------------------------------------------------------------------------
__global__ void wt_transpose_kernel(const float* __restrict__ w,
                                    float* __restrict__ wt) {
    int i = blockIdx.x * 256 + threadIdx.x;       // i = (t*64 + c)*64 + o
    if (i < 9 * CIN * COUT) {
        int o = i & 63;
        int c = (i >> 6) & 63;
        int t = i >> 12;
        wt[i] = w[(o * CIN + c) * 9 + t];
    }
}

// ---------------------------------------------------------------------------
// Main kernel: 256 threads (4 waves) per 64 consecutive output pixels.
// lane = pixel (same 64 pixels for all 4 waves); wave w covers INPUT
// channels [16w,16w+16) and accumulates ALL 64 output channels in registers
// (static indices only — round-2 lesson). Weight offset is forced uniform
// via readfirstlane (round-3 lesson: wave*16 isn't provably uniform, the
// compiler demoted weights to per-lane VMEM loads -> 74M VMEM instrs).
// Cross-wave reduction via LDS in 4 statically-unrolled chunks of 16,
// rows padded to 21 floats (gcd(21,32)=1 -> conflict-free).
// ---------------------------------------------------------------------------
__global__ __launch_bounds__(256) void pdconv_kernel(
    const float* __restrict__ in,        // [B][CIN][H][W]
    const float* __restrict__ wt,        // [9][CIN][COUT]
    const float* __restrict__ rate_map,  // [B][1][H][W]
    const float* __restrict__ bias,      // [COUT]
    float* __restrict__ out)             // [B][COUT][H][W]
{
    const int tid  = threadIdx.x;
    const int lane = tid & 63;
    const int wave = tid >> 6;

    // XCD-bijective swizzle (1600 % 8 == 0): contiguous band per XCD.
    const int cpx = gridDim.x >> 3;                       // 200
    const int bid = (blockIdx.x & 7) * cpx + (blockIdx.x >> 3);

    const int p    = bid * 64 + lane;       // flat pixel over (b,y,x)
    const int b    = p / HW;                // 25600 % 64 == 0
    const int pix  = p - b * HW;
    const int y    = pix / WW;
    const int x    = pix - y * WW;

    const float rate = rate_map[p];
    const float fy = (float)y, fx = (float)x;

    float acc[COUT];
#pragma unroll
    for (int o = 0; o < COUT; ++o) acc[o] = 0.0f;

    const int c0 = wave * 16;               // this wave's input channels
    const float* img = in + ((size_t)b * CIN + c0) * HW;

#pragma unroll 1
    for (int t = 0; t < 9; ++t) {
        const int ky = t / 3;
        const int kx = t - 3 * ky;

        const float sy  = fy + (float)(ky - 1) * rate;
        const float sx  = fx + (float)(kx - 1) * rate;
        const float y0f = floorf(sy), x0f = floorf(sx);
        const float wy  = sy - y0f,   wx  = sx - x0f;
        const int   y0  = (int)y0f,   x0  = (int)x0f;
        const int   y1  = y0 + 1,     x1  = x0 + 1;

        const float omwy = 1.0f - wy, omwx = 1.0f - wx;
        const float vy0 = (y0 >= 0 && y0 < HH) ? 1.0f : 0.0f;
        const float vy1 = (y1 >= 0 && y1 < HH) ? 1.0f : 0.0f;
        const float vx0 = (x0 >= 0 && x0 < WW) ? 1.0f : 0.0f;
        const float vx1 = (x1 >= 0 && x1 < WW) ? 1.0f : 0.0f;

        const float c00 = omwy * omwx * vy0 * vx0;
        const float c01 = omwy * wx   * vy0 * vx1;
        const float c10 = wy   * omwx * vy1 * vx0;
        const float c11 = wy   * wx   * vy1 * vx1;

        const int cy0 = min(max(y0, 0), HH - 1);
        const int cy1 = min(max(y1, 0), HH - 1);
        const int cx0 = min(max(x0, 0), WW - 1);
        const int cx1 = min(max(x1, 0), WW - 1);

        const int i00 = cy0 * WW + cx0;
        const int i01 = cy0 * WW + cx1;
        const int i10 = cy1 * WW + cx0;
        const int i11 = cy1 * WW + cx1;

        // software-pipelined over cc: gathers for cc+1 issue before cc's fmacs
        float v00 = img[i00], v01 = img[i01], v10 = img[i10], v11 = img[i11];
#pragma unroll 1
        for (int cc = 0; cc < 15; ++cc) {
            const float a = c00 * v00 + c01 * v01 + c10 * v10 + c11 * v11;
            const float* nxt = img + (size_t)(cc + 1) * HW;
            v00 = nxt[i00]; v01 = nxt[i01]; v10 = nxt[i10]; v11 = nxt[i11];
            // wave-uniform weight row -> SGPR (readfirstlane forces it)
            const int woff = __builtin_amdgcn_readfirstlane(
                (t * CIN + c0 + cc) * COUT);
            const float* wr = wt + woff;
#pragma unroll
            for (int o = 0; o < COUT; ++o)
                acc[o] = fmaf(wr[o], a, acc[o]);
        }
        {   // epilogue cc = 15
            const float a = c00 * v00 + c01 * v01 + c10 * v10 + c11 * v11;
            const int woff = __builtin_amdgcn_readfirstlane(
                (t * CIN + c0 + 15) * COUT);
            const float* wr = wt + woff;
#pragma unroll
            for (int o = 0; o < COUT; ++o)
                acc[o] = fmaf(wr[o], a, acc[o]);
        }
    }

    // ---- cross-wave reduction via LDS, 4 static chunks of 16 outputs ----
    __shared__ float red[4][64][21];        // stride 21: gcd(21,32)=1 -> free
    float* op = out + (size_t)b * COUT * HW + pix;

#pragma unroll
    for (int chunk = 0; chunk < 4; ++chunk) {
#pragma unroll
        for (int j = 0; j < 16; ++j)
            red[wave][lane][j] = acc[chunk * 16 + j];   // static acc index
        __syncthreads();
#pragma unroll
        for (int jj = 0; jj < 4; ++jj) {
            const int j = wave * 4 + jj;                // LDS idx: runtime OK
            const float s = red[0][lane][j] + red[1][lane][j]
                          + red[2][lane][j] + red[3][lane][j];
            const int o = chunk * 16 + j;
            op[(size_t)o * HW] = s + bias[o];
        }
        __syncthreads();
    }
}

extern "C" void kernel_launch(void* const* d_in, const int* in_sizes, int n_in,
                              void* d_out, int out_size, void* d_ws, size_t ws_size,
                              hipStream_t stream) {
    (void)in_sizes; (void)n_in; (void)out_size; (void)ws_size;
    const float* in   = (const float*)d_in[0];
    const float* w    = (const float*)d_in[1];
    const float* rm   = (const float*)d_in[2];
    const float* bias = (const float*)d_in[3];
    float* out = (float*)d_out;
    float* wtb = (float*)d_ws;   // 147,456 B scratch for transposed weight

    hipLaunchKernelGGL(wt_transpose_kernel, dim3(144), dim3(256), 0, stream, w, wtb);

    const int nblocks = (NB * HW) / 64;  // 1600
    hipLaunchKernelGGL(pdconv_kernel, dim3(nblocks), dim3(256), 0, stream,
                       in, wtb, rm, bias, out);
}

// Round 7
// 169.810 us; speedup vs baseline: 5.3733x; 1.1239x over previous
//
#include <hip/hip_runtime.h>
#include <hip/hip_bf16.h>

#define NB   4
#define CIN  64
#define COUT 64
#define HH   160
#define WW   160
#define HW   (HH * WW)

typedef __attribute__((ext_vector_type(8))) short bf16x8;   // 8 bf16 = 4 VGPR
typedef __attribute__((ext_vector_type(4))) float f32x4;

// ---------------------------------------------------------------------------
// Pre-pass: weight [O][C][3][3] f32 -> wt2[t][o][c] bf16 (t = ky*3+kx).
// A-operand frag (row o = lane&15, k-octet by lane>>4) then reads 16 B
// contiguous per lane.
// ---------------------------------------------------------------------------
__global__ void wt2_kernel(const float* __restrict__ w, short* __restrict__ wt2) {
    int i = blockIdx.x * 256 + threadIdx.x;       // i = (t*64 + o)*64 + c
    if (i < 9 * COUT * CIN) {
        int c = i & 63;
        int o = (i >> 6) & 63;
        int t = i >> 12;
        wt2[i] = __builtin_bit_cast(short, __float2bfloat16(w[(o * CIN + c) * 9 + t]));
    }
}

// ---------------------------------------------------------------------------
// MFMA kernel: 4 independent waves / block, each owns a 16-pixel strip
// (HW % 16 == 0 and W = 160 = 10*16 -> strip never wraps a row; y uniform).
// Per wave: C[64 o][16 px] = sum_k W[o][k] * A[k][px], k = (t,c), K = 576.
//   A-operand = weights  (row o = lane&15 + 16*mt, k = 8*(lane>>4)+j)
//   B-operand = bilinear pixel values (col px = lane&15, same k-octet)
// Lane l therefore computes pixel (l&15)'s values for channels
// 32*ks + 8*(l>>4) + j  -- geometry is shared by all 4 lane-groups (wave
// computes it once), gathers are the same 4-corner pattern as before.
// C/D: col = lane&15 = px, row = 4*(lane>>4)+r = o-offset -> stores land in
// 64 B-contiguous 16-lane segments. No LDS, no barriers anywhere.
// ---------------------------------------------------------------------------
__global__ __launch_bounds__(256) void pdconv_mfma_kernel(
    const float* __restrict__ in,        // [B][CIN][H][W] f32
    const short* __restrict__ wt2,       // [9][COUT][CIN] bf16
    const float* __restrict__ rate_map,  // [B][1][H][W] f32
    const float* __restrict__ bias,      // [COUT] f32
    float* __restrict__ out)             // [B][COUT][H][W] f32
{
    const int tid  = threadIdx.x;
    const int wave = tid >> 6;
    const int lane = tid & 63;
    const int px   = lane & 15;          // pixel-in-strip (B-operand col)
    const int g    = lane >> 4;          // k-octet selector

    // XCD-bijective swizzle (1600 % 8 == 0): contiguous band per XCD.
    const int cpx = gridDim.x >> 3;                       // 200
    const int bid = (blockIdx.x & 7) * cpx + (blockIdx.x >> 3);

    const int base = bid * 64 + wave * 16;   // this wave's 16-px strip
    const int b    = base / HW;              // HW % 16 == 0: strip in one image
    const int pix0 = base - b * HW;
    const int y    = pix0 / WW;              // strip within one row (16 | 160)
    const int x0   = pix0 - y * WW;
    const int x    = x0 + px;

    const float rate = rate_map[base + px];  // lanes l, l+16,... share value
    const float fy = (float)y, fx = (float)x;

    f32x4 acc[4];
#pragma unroll
    for (int mt = 0; mt < 4; ++mt) acc[mt] = (f32x4){0.f, 0.f, 0.f, 0.f};

    const float* img  = in + (size_t)b * CIN * HW;
    const float* imgg = img + (size_t)g * 8 * HW;   // octet-group channel base

#pragma unroll 1
    for (int t = 0; t < 9; ++t) {
        const int ky = t / 3;
        const int kx = t - 3 * ky;

        // ---- per-pixel bilinear geometry (same math as verified fp32 ver) ----
        const float sy  = fy + (float)(ky - 1) * rate;
        const float sx  = fx + (float)(kx - 1) * rate;
        const float y0f = floorf(sy), x0f = floorf(sx);
        const float wy  = sy - y0f,   wx  = sx - x0f;
        const int   y0  = (int)y0f,   x0i = (int)x0f;
        const int   y1  = y0 + 1,     x1  = x0i + 1;

        const float omwy = 1.0f - wy, omwx = 1.0f - wx;
        const float vy0 = (y0 >= 0 && y0 < HH) ? 1.0f : 0.0f;
        const float vy1 = (y1 >= 0 && y1 < HH) ? 1.0f : 0.0f;
        const float vx0 = (x0i >= 0 && x0i < WW) ? 1.0f : 0.0f;
        const float vx1 = (x1 >= 0 && x1 < WW) ? 1.0f : 0.0f;

        const float c00 = omwy * omwx * vy0 * vx0;
        const float c01 = omwy * wx   * vy0 * vx1;
        const float c10 = wy   * omwx * vy1 * vx0;
        const float c11 = wy   * wx   * vy1 * vx1;

        const int cy0 = min(max(y0, 0), HH - 1);
        const int cy1 = min(max(y1, 0), HH - 1);
        const int cx0 = min(max(x0i, 0), WW - 1);
        const int cx1 = min(max(x1, 0), WW - 1);

        const int i00 = cy0 * WW + cx0;
        const int i01 = cy0 * WW + cx1;
        const int i10 = cy1 * WW + cx0;
        const int i11 = cy1 * WW + cx1;

#pragma unroll
        for (int ks = 0; ks < 2; ++ks) {
            // ---- weight A-frags for this K-half (16 B contiguous per lane) ----
            bf16x8 wf[4];
#pragma unroll
            for (int mt = 0; mt < 4; ++mt)
                wf[mt] = *(const bf16x8*)(wt2 +
                          ((t * COUT + 16 * mt + px) * CIN + 32 * ks + 8 * g));

            // ---- bilinear values for channels c = 32*ks + 8*g + j ----
            float a[8];
#pragma unroll
            for (int j = 0; j < 8; ++j) {
                const float* ch = imgg + (size_t)(32 * ks + j) * HW;
                a[j] = c00 * ch[i00] + c01 * ch[i01]
                     + c10 * ch[i10] + c11 * ch[i11];
            }

            union { bf16x8 v; short s[8]; } pf;
#pragma unroll
            for (int j = 0; j < 8; ++j)
                pf.s[j] = __builtin_bit_cast(short, __float2bfloat16(a[j]));

#pragma unroll
            for (int mt = 0; mt < 4; ++mt)
                acc[mt] = __builtin_amdgcn_mfma_f32_16x16x32_bf16(
                              wf[mt], pf.v, acc[mt], 0, 0, 0);
        }
    }

    // ---- epilogue: C[o][px], o = 16*mt + 4*g + r; 16-lane 64 B segments ----
    float* op = out + (size_t)b * COUT * HW + pix0 + px;
#pragma unroll
    for (int mt = 0; mt < 4; ++mt) {
#pragma unroll
        for (int r = 0; r < 4; ++r) {
            const int o = 16 * mt + 4 * g + r;
            op[(size_t)o * HW] = acc[mt][r] + bias[o];
        }
    }
}

extern "C" void kernel_launch(void* const* d_in, const int* in_sizes, int n_in,
                              void* d_out, int out_size, void* d_ws, size_t ws_size,
                              hipStream_t stream) {
    (void)in_sizes; (void)n_in; (void)out_size; (void)ws_size;
    const float* in   = (const float*)d_in[0];
    const float* w    = (const float*)d_in[1];
    const float* rm   = (const float*)d_in[2];
    const float* bias = (const float*)d_in[3];
    float* out = (float*)d_out;
    short* wt2 = (short*)d_ws;   // 73,728 B bf16 transposed weight

    hipLaunchKernelGGL(wt2_kernel, dim3(144), dim3(256), 0, stream, w, wt2);

    const int nblocks = (NB * HW) / 64;  // 1600 blocks x 4 waves x 16 px
    hipLaunchKernelGGL(pdconv_mfma_kernel, dim3(nblocks), dim3(256), 0, stream,
                       in, wt2, rm, bias, out);
}

// Round 8
// 92.798 us; speedup vs baseline: 9.8325x; 1.8299x over previous
//
#include <hip/hip_runtime.h>
#include <hip/hip_bf16.h>

#define NB   4
#define CIN  64
#define COUT 64
#define HH   160
#define WW   160
#define HW   (HH * WW)

typedef __attribute__((ext_vector_type(8))) short bf16x8;   // 8 bf16 = 4 VGPR
typedef __attribute__((ext_vector_type(4))) float f32x4;
typedef __attribute__((ext_vector_type(4))) unsigned int u32x4;

static __device__ __forceinline__ short f2bf(float v) {
    return __builtin_bit_cast(short, __float2bfloat16(v));
}

// ---------------------------------------------------------------------------
// Pre-pass 1: weight [O][C][3][3] f32 -> wtf in exact A-fragment order:
// wtf[t][ks][mt][lane][j]  (lane 0..63, j 0..7), so a wave's A-frag load is
// one contiguous 1 KB block: lane reads wtf + frag*512 + lane*8 (16 B).
//   o = 16*mt + (lane&15),  c = 32*ks + 8*(lane>>4) + j
// ---------------------------------------------------------------------------
__global__ void wtf_kernel(const float* __restrict__ w, short* __restrict__ wtf) {
    int i = blockIdx.x * 256 + threadIdx.x;   // 9*2*4*64*8 = 36864
    if (i < 36864) {
        const int j  = i & 7;
        const int l  = (i >> 3) & 63;
        const int mt = (i >> 9) & 3;
        const int ks = (i >> 11) & 1;
        const int t  = i >> 12;
        const int o  = 16 * mt + (l & 15);
        const int c  = 32 * ks + 8 * (l >> 4) + j;
        wtf[i] = f2bf(w[(o * CIN + c) * 9 + t]);
    }
}

// ---------------------------------------------------------------------------
// Pre-pass 2: input [B][C][H][W] f32 -> tin [B][H][W][C] bf16.
// Thread per pixel; for fixed c the wave reads 64 consecutive hw (coalesced);
// writes 4 x 32 B contiguous per thread.
// ---------------------------------------------------------------------------
__global__ __launch_bounds__(256) void tin_kernel(const float* __restrict__ in,
                                                  short* __restrict__ tin) {
    const int gid = blockIdx.x * 256 + threadIdx.x;   // b*HW + hw
    if (gid >= NB * HW) return;
    const int b  = gid / HW;
    const int hw = gid - b * HW;
    const float* src = in + (size_t)b * CIN * HW + hw;
    short* dst = tin + (size_t)gid * CIN;
#pragma unroll
    for (int chunk = 0; chunk < 4; ++chunk) {
        union { u32x4 v; short s[8]; } p0, p1;
#pragma unroll
        for (int cc = 0; cc < 8; ++cc)
            p0.s[cc] = f2bf(src[(size_t)(chunk * 16 + cc) * HW]);
#pragma unroll
        for (int cc = 0; cc < 8; ++cc)
            p1.s[cc] = f2bf(src[(size_t)(chunk * 16 + 8 + cc) * HW]);
        *(u32x4*)(dst + chunk * 16)     = p0.v;
        *(u32x4*)(dst + chunk * 16 + 8) = p1.v;
    }
}

// ---------------------------------------------------------------------------
// Main MFMA kernel (NHWC-bf16 input): 4 waves/block, each owns a 16-px strip.
// Per wave: C[64 o][16 px] = sum_k W[o][k]*A[k][px], k=(t,c), K=576.
// Lane (px = lane&15, g = lane>>4):
//   input: one vaddr per corner (i*128 + 16g bytes); ks0/ks1 via imm +-64 B;
//          each load is a contiguous 16 B dwordx4 (channels adjacent in NHWC)
//   weights: wtf frag order -> wave-contiguous 1 KB per A-frag
// 72 input + 72 weight VMEM loads per wave total (vs 576+72 in NCHW version).
// ---------------------------------------------------------------------------
__global__ __launch_bounds__(256) void pdconv_nhwc_kernel(
    const short* __restrict__ tin,       // [B][H][W][CIN] bf16
    const short* __restrict__ wtf,       // frag-ordered weights bf16
    const float* __restrict__ rate_map,  // [B][1][H][W] f32
    const float* __restrict__ bias,      // [COUT] f32
    float* __restrict__ out)             // [B][COUT][H][W] f32
{
    const int tid  = threadIdx.x;
    const int wave = tid >> 6;
    const int lane = tid & 63;
    const int px   = lane & 15;
    const int g    = lane >> 4;

    // XCD-bijective swizzle (1600 % 8 == 0)
    const int cpx = gridDim.x >> 3;
    const int bid = (blockIdx.x & 7) * cpx + (blockIdx.x >> 3);

    const int base = bid * 64 + wave * 16;
    const int b    = base / HW;
    const int pix0 = base - b * HW;
    const int y    = pix0 / WW;              // 16 | 160: strip within one row
    const int x0   = pix0 - y * WW;
    const int x    = x0 + px;

    const float rate = rate_map[base + px];
    const float fy = (float)y, fx = (float)x;

    f32x4 acc[4];
#pragma unroll
    for (int mt = 0; mt < 4; ++mt) acc[mt] = (f32x4){0.f, 0.f, 0.f, 0.f};

    const short* tb = tin + (size_t)b * HW * CIN + 8 * g;   // lane channel base

#pragma unroll 1
    for (int t = 0; t < 9; ++t) {
        const int ky = t / 3;
        const int kx = t - 3 * ky;

        const float sy  = fy + (float)(ky - 1) * rate;
        const float sx  = fx + (float)(kx - 1) * rate;
        const float y0f = floorf(sy), x0f = floorf(sx);
        const float wy  = sy - y0f,   wx  = sx - x0f;
        const int   y0  = (int)y0f,   x0i = (int)x0f;
        const int   y1  = y0 + 1,     x1  = x0i + 1;

        const float omwy = 1.0f - wy, omwx = 1.0f - wx;
        const float vy0 = (y0 >= 0 && y0 < HH) ? 1.0f : 0.0f;
        const float vy1 = (y1 >= 0 && y1 < HH) ? 1.0f : 0.0f;
        const float vx0 = (x0i >= 0 && x0i < WW) ? 1.0f : 0.0f;
        const float vx1 = (x1 >= 0 && x1 < WW) ? 1.0f : 0.0f;

        const float c00 = omwy * omwx * vy0 * vx0;
        const float c01 = omwy * wx   * vy0 * vx1;
        const float c10 = wy   * omwx * vy1 * vx0;
        const float c11 = wy   * wx   * vy1 * vx1;

        const int cy0 = min(max(y0, 0), HH - 1);
        const int cy1 = min(max(y1, 0), HH - 1);
        const int cx0 = min(max(x0i, 0), WW - 1);
        const int cx1 = min(max(x1, 0), WW - 1);

        // corner base pointers (shorts); ks1 = +32 shorts (64 B) imm offset
        const short* p00 = tb + (size_t)(cy0 * WW + cx0) * CIN;
        const short* p01 = tb + (size_t)(cy0 * WW + cx1) * CIN;
        const short* p10 = tb + (size_t)(cy1 * WW + cx0) * CIN;
        const short* p11 = tb + (size_t)(cy1 * WW + cx1) * CIN;

        // 8 input loads (16 B each, contiguous channels)
        u32x4 v00[2], v01[2], v10[2], v11[2];
#pragma unroll
        for (int ks = 0; ks < 2; ++ks) {
            v00[ks] = *(const u32x4*)(p00 + 32 * ks);
            v01[ks] = *(const u32x4*)(p01 + 32 * ks);
            v10[ks] = *(const u32x4*)(p10 + 32 * ks);
            v11[ks] = *(const u32x4*)(p11 + 32 * ks);
        }

        // 8 weight A-frags (wave-contiguous 1 KB each)
        bf16x8 wf[2][4];
#pragma unroll
        for (int ks = 0; ks < 2; ++ks)
#pragma unroll
            for (int mt = 0; mt < 4; ++mt)
                wf[ks][mt] = *(const bf16x8*)(wtf +
                              (size_t)((t * 2 + ks) * 4 + mt) * 512 + lane * 8);

#pragma unroll
        for (int ks = 0; ks < 2; ++ks) {
            // bilinear in f32 via 1-op bf16->f32 bit extraction
            union { bf16x8 v; short s[8]; } pf;
#pragma unroll
            for (int wd = 0; wd < 4; ++wd) {
                const unsigned int u00 = v00[ks][wd], u01 = v01[ks][wd];
                const unsigned int u10 = v10[ks][wd], u11 = v11[ks][wd];
                float lo, hi;
                lo  = c00 * __builtin_bit_cast(float, u00 << 16);
                hi  = c00 * __builtin_bit_cast(float, u00 & 0xffff0000u);
                lo += c01 * __builtin_bit_cast(float, u01 << 16);
                hi += c01 * __builtin_bit_cast(float, u01 & 0xffff0000u);
                lo += c10 * __builtin_bit_cast(float, u10 << 16);
                hi += c10 * __builtin_bit_cast(float, u10 & 0xffff0000u);
                lo += c11 * __builtin_bit_cast(float, u11 << 16);
                hi += c11 * __builtin_bit_cast(float, u11 & 0xffff0000u);
                pf.s[2 * wd]     = f2bf(lo);
                pf.s[2 * wd + 1] = f2bf(hi);
            }
#pragma unroll
            for (int mt = 0; mt < 4; ++mt)
                acc[mt] = __builtin_amdgcn_mfma_f32_16x16x32_bf16(
                              wf[ks][mt], pf.v, acc[mt], 0, 0, 0);
        }
    }

    // epilogue: C col = px, row = 4g + r (+16mt); bias via float4 loads
    float* op = out + (size_t)b * COUT * HW + pix0 + px;
#pragma unroll
    for (int mt = 0; mt < 4; ++mt) {
        const f32x4 bv = *(const f32x4*)(bias + 16 * mt + 4 * g);
#pragma unroll
        for (int r = 0; r < 4; ++r) {
            const int o = 16 * mt + 4 * g + r;
            op[(size_t)o * HW] = acc[mt][r] + bv[r];
        }
    }
}

// ---------------------------------------------------------------------------
// Fallback (round-7 NCHW path) if ws_size can't hold the transposed input.
// ---------------------------------------------------------------------------
__global__ void wt2_kernel(const float* __restrict__ w, short* __restrict__ wt2) {
    int i = blockIdx.x * 256 + threadIdx.x;
    if (i < 9 * COUT * CIN) {
        int c = i & 63, o = (i >> 6) & 63, t = i >> 12;
        wt2[i] = f2bf(w[(o * CIN + c) * 9 + t]);
    }
}

__global__ __launch_bounds__(256) void pdconv_mfma_kernel(
    const float* __restrict__ in, const short* __restrict__ wt2,
    const float* __restrict__ rate_map, const float* __restrict__ bias,
    float* __restrict__ out)
{
    const int tid = threadIdx.x, wave = tid >> 6, lane = tid & 63;
    const int px = lane & 15, g = lane >> 4;
    const int cpx = gridDim.x >> 3;
    const int bid = (blockIdx.x & 7) * cpx + (blockIdx.x >> 3);
    const int base = bid * 64 + wave * 16;
    const int b = base / HW, pix0 = base - b * HW;
    const int y = pix0 / WW, x0 = pix0 - y * WW, x = x0 + px;
    const float rate = rate_map[base + px];
    const float fy = (float)y, fx = (float)x;
    f32x4 acc[4];
#pragma unroll
    for (int mt = 0; mt < 4; ++mt) acc[mt] = (f32x4){0.f, 0.f, 0.f, 0.f};
    const float* img  = in + (size_t)b * CIN * HW;
    const float* imgg = img + (size_t)g * 8 * HW;
#pragma unroll 1
    for (int t = 0; t < 9; ++t) {
        const int ky = t / 3, kx = t - 3 * ky;
        const float sy = fy + (float)(ky - 1) * rate;
        const float sx = fx + (float)(kx - 1) * rate;
        const float y0f = floorf(sy), x0f = floorf(sx);
        const float wy = sy - y0f, wx = sx - x0f;
        const int y0 = (int)y0f, x0i = (int)x0f, y1 = y0 + 1, x1 = x0i + 1;
        const float omwy = 1.0f - wy, omwx = 1.0f - wx;
        const float vy0 = (y0 >= 0 && y0 < HH) ? 1.0f : 0.0f;
        const float vy1 = (y1 >= 0 && y1 < HH) ? 1.0f : 0.0f;
        const float vx0 = (x0i >= 0 && x0i < WW) ? 1.0f : 0.0f;
        const float vx1 = (x1 >= 0 && x1 < WW) ? 1.0f : 0.0f;
        const float c00 = omwy * omwx * vy0 * vx0, c01 = omwy * wx * vy0 * vx1;
        const float c10 = wy * omwx * vy1 * vx0,  c11 = wy * wx * vy1 * vx1;
        const int cy0 = min(max(y0, 0), HH - 1), cy1 = min(max(y1, 0), HH - 1);
        const int cx0 = min(max(x0i, 0), WW - 1), cx1 = min(max(x1, 0), WW - 1);
        const int i00 = cy0 * WW + cx0, i01 = cy0 * WW + cx1;
        const int i10 = cy1 * WW + cx0, i11 = cy1 * WW + cx1;
#pragma unroll
        for (int ks = 0; ks < 2; ++ks) {
            bf16x8 wf[4];
#pragma unroll
            for (int mt = 0; mt < 4; ++mt)
                wf[mt] = *(const bf16x8*)(wt2 +
                          ((t * COUT + 16 * mt + px) * CIN + 32 * ks + 8 * g));
            float a[8];
#pragma unroll
            for (int j = 0; j < 8; ++j) {
                const float* ch = imgg + (size_t)(32 * ks + j) * HW;
                a[j] = c00 * ch[i00] + c01 * ch[i01] + c10 * ch[i10] + c11 * ch[i11];
            }
            union { bf16x8 v; short s[8]; } pf;
#pragma unroll
            for (int j = 0; j < 8; ++j) pf.s[j] = f2bf(a[j]);
#pragma unroll
            for (int mt = 0; mt < 4; ++mt)
                acc[mt] = __builtin_amdgcn_mfma_f32_16x16x32_bf16(
                              wf[mt], pf.v, acc[mt], 0, 0, 0);
        }
    }
    float* op = out + (size_t)b * COUT * HW + pix0 + px;
#pragma unroll
    for (int mt = 0; mt < 4; ++mt)
#pragma unroll
        for (int r = 0; r < 4; ++r) {
            const int o = 16 * mt + 4 * g + r;
            op[(size_t)o * HW] = acc[mt][r] + bias[o];
        }
}

extern "C" void kernel_launch(void* const* d_in, const int* in_sizes, int n_in,
                              void* d_out, int out_size, void* d_ws, size_t ws_size,
                              hipStream_t stream) {
    (void)in_sizes; (void)n_in; (void)out_size;
    const float* in   = (const float*)d_in[0];
    const float* w    = (const float*)d_in[1];
    const float* rm   = (const float*)d_in[2];
    const float* bias = (const float*)d_in[3];
    float* out = (float*)d_out;

    const size_t WTF_BYTES = 36864 * sizeof(short);                 // 73,728
    const size_t TIN_BYTES = (size_t)NB * HW * CIN * sizeof(short); // 13,107,200
    const int nblocks = (NB * HW) / 64;                             // 1600

    if (ws_size >= WTF_BYTES + TIN_BYTES) {
        short* wtf = (short*)d_ws;
        short* tin = (short*)((char*)d_ws + WTF_BYTES);
        hipLaunchKernelGGL(wtf_kernel, dim3(144), dim3(256), 0, stream, w, wtf);
        hipLaunchKernelGGL(tin_kernel, dim3((NB * HW + 255) / 256), dim3(256),
                           0, stream, in, tin);
        hipLaunchKernelGGL(pdconv_nhwc_kernel, dim3(nblocks), dim3(256), 0,
                           stream, tin, wtf, rm, bias, out);
    } else {
        short* wt2 = (short*)d_ws;   // 73,728 B
        hipLaunchKernelGGL(wt2_kernel, dim3(144), dim3(256), 0, stream, w, wt2);
        hipLaunchKernelGGL(pdconv_mfma_kernel, dim3(nblocks), dim3(256), 0,
                           stream, in, wt2, rm, bias, out);
    }
}

// Round 9
// 87.642 us; speedup vs baseline: 10.4109x; 1.0588x over previous
//
#include <hip/hip_runtime.h>
#include <hip/hip_bf16.h>

#define NB   4
#define CIN  64
#define COUT 64
#define HH   160
#define WW   160
#define HW   (HH * WW)

typedef __attribute__((ext_vector_type(8))) short bf16x8;   // 8 bf16 = 4 VGPR
typedef __attribute__((ext_vector_type(4))) float f32x4;
typedef __attribute__((ext_vector_type(4))) unsigned int u32x4;

static __device__ __forceinline__ short f2bf(float v) {
    return __builtin_bit_cast(short, __float2bfloat16(v));
}

// ---------------------------------------------------------------------------
// Pre-pass 1: weight [O][C][3][3] f32 -> wtf in exact A-fragment order:
// wtf[t][ks][mt][lane][j]; a wave's A-frag load = one contiguous 1 KB block.
//   o = 16*mt + (lane&15),  c = 32*ks + 8*(lane>>4) + j
// ---------------------------------------------------------------------------
__global__ void wtf_kernel(const float* __restrict__ w, short* __restrict__ wtf) {
    int i = blockIdx.x * 256 + threadIdx.x;   // 9*2*4*64*8 = 36864
    if (i < 36864) {
        const int j  = i & 7;
        const int l  = (i >> 3) & 63;
        const int mt = (i >> 9) & 3;
        const int ks = (i >> 11) & 1;
        const int t  = i >> 12;
        const int o  = 16 * mt + (l & 15);
        const int c  = 32 * ks + 8 * (l >> 4) + j;
        wtf[i] = f2bf(w[(o * CIN + c) * 9 + t]);
    }
}

// ---------------------------------------------------------------------------
// Pre-pass 2: input [B][C][H][W] f32 -> tin [B][H][W][C] bf16.
// ---------------------------------------------------------------------------
__global__ __launch_bounds__(256) void tin_kernel(const float* __restrict__ in,
                                                  short* __restrict__ tin) {
    const int gid = blockIdx.x * 256 + threadIdx.x;   // b*HW + hw
    if (gid >= NB * HW) return;
    const int b  = gid / HW;
    const int hw = gid - b * HW;
    const float* src = in + (size_t)b * CIN * HW + hw;
    short* dst = tin + (size_t)gid * CIN;
#pragma unroll
    for (int chunk = 0; chunk < 4; ++chunk) {
        union { u32x4 v; short s[8]; } p0, p1;
#pragma unroll
        for (int cc = 0; cc < 8; ++cc)
            p0.s[cc] = f2bf(src[(size_t)(chunk * 16 + cc) * HW]);
#pragma unroll
        for (int cc = 0; cc < 8; ++cc)
            p1.s[cc] = f2bf(src[(size_t)(chunk * 16 + 8 + cc) * HW]);
        *(u32x4*)(dst + chunk * 16)     = p0.v;
        *(u32x4*)(dst + chunk * 16 + 8) = p1.v;
    }
}

// Geometry for tap T -> 4 bilinear coefs + 4 corner pointers (from tb).
#define GEOM(T, C00, C01, C10, C11, Q00, Q01, Q10, Q11) do {                 \
    const int gky = (T) / 3, gkx = (T) - 3 * gky;                            \
    const float gsy = fy + (float)(gky - 1) * rate;                          \
    const float gsx = fx + (float)(gkx - 1) * rate;                          \
    const float gy0f = floorf(gsy), gx0f = floorf(gsx);                      \
    const float gwy = gsy - gy0f, gwx = gsx - gx0f;                          \
    const int gy0 = (int)gy0f, gx0 = (int)gx0f;                              \
    const int gy1 = gy0 + 1, gx1 = gx0 + 1;                                  \
    const float gomwy = 1.0f - gwy, gomwx = 1.0f - gwx;                      \
    const float gvy0 = (gy0 >= 0 && gy0 < HH) ? 1.0f : 0.0f;                 \
    const float gvy1 = (gy1 >= 0 && gy1 < HH) ? 1.0f : 0.0f;                 \
    const float gvx0 = (gx0 >= 0 && gx0 < WW) ? 1.0f : 0.0f;                 \
    const float gvx1 = (gx1 >= 0 && gx1 < WW) ? 1.0f : 0.0f;                 \
    C00 = gomwy * gomwx * gvy0 * gvx0;                                       \
    C01 = gomwy * gwx   * gvy0 * gvx1;                                       \
    C10 = gwy   * gomwx * gvy1 * gvx0;                                       \
    C11 = gwy   * gwx   * gvy1 * gvx1;                                       \
    const int gcy0 = min(max(gy0, 0), HH - 1);                               \
    const int gcy1 = min(max(gy1, 0), HH - 1);                               \
    const int gcx0 = min(max(gx0, 0), WW - 1);                               \
    const int gcx1 = min(max(gx1, 0), WW - 1);                               \
    Q00 = tb + (size_t)(gcy0 * WW + gcx0) * CIN;                             \
    Q01 = tb + (size_t)(gcy0 * WW + gcx1) * CIN;                             \
    Q10 = tb + (size_t)(gcy1 * WW + gcx0) * CIN;                             \
    Q11 = tb + (size_t)(gcy1 * WW + gcx1) * CIN;                             \
} while (0)

// ---------------------------------------------------------------------------
// Main kernel: block = 4 waves = 2 strips x 2 K-halves (split-K over input
// channels). Wave (strip, ks) computes C[64 o][16 px] over c in
// [32ks, 32ks+32): per tap 4 input loads (16 B NHWC) + 4 weight frags +
// 4 MFMA. Tap t+1's loads are issued before tap t's bilinear/MFMA
// (software pipeline) to hide L2/L3 latency. Pair-reduction via LDS
// (stride 17 -> 2-way bank = free), one barrier, static acc indexing.
// ---------------------------------------------------------------------------
__global__ __launch_bounds__(256, 3) void pdconv_split_kernel(
    const short* __restrict__ tin,       // [B][H][W][CIN] bf16
    const short* __restrict__ wtf,       // frag-ordered weights bf16
    const float* __restrict__ rate_map,  // [B][1][H][W] f32
    const float* __restrict__ bias,      // [COUT] f32
    float* __restrict__ out)             // [B][COUT][H][W] f32
{
    const int tid   = threadIdx.x;
    const int wave  = tid >> 6;
    const int lane  = tid & 63;
    const int px    = lane & 15;
    const int g     = lane >> 4;
    const int strip = wave >> 1;
    const int ks    = wave & 1;

    // XCD-bijective swizzle (3200 % 8 == 0)
    const int cpx = gridDim.x >> 3;                     // 400
    const int bid = (blockIdx.x & 7) * cpx + (blockIdx.x >> 3);

    const int base = bid * 32 + strip * 16;             // this wave's strip
    const int b    = base / HW;
    const int pix0 = base - b * HW;
    const int y    = pix0 / WW;                         // 16 | 160
    const int x0   = pix0 - y * WW;
    const int x    = x0 + px;

    const float rate = rate_map[base + px];
    const float fy = (float)y, fx = (float)x;

    const short* tb  = tin + (size_t)b * HW * CIN + 32 * ks + 8 * g;
    const short* wtb = wtf + (size_t)ks * 2048 + lane * 8;   // + t*4096 + mt*512

    f32x4 acc[4];
#pragma unroll
    for (int mt = 0; mt < 4; ++mt) acc[mt] = (f32x4){0.f, 0.f, 0.f, 0.f};

    // ---- prologue: tap 0 geometry + loads ----
    float c00, c01, c10, c11;
    const short *q00, *q01, *q10, *q11;
    GEOM(0, c00, c01, c10, c11, q00, q01, q10, q11);
    u32x4 v00 = *(const u32x4*)q00;
    u32x4 v01 = *(const u32x4*)q01;
    u32x4 v10 = *(const u32x4*)q10;
    u32x4 v11 = *(const u32x4*)q11;
    bf16x8 wf0 = *(const bf16x8*)(wtb);
    bf16x8 wf1 = *(const bf16x8*)(wtb + 512);
    bf16x8 wf2 = *(const bf16x8*)(wtb + 1024);
    bf16x8 wf3 = *(const bf16x8*)(wtb + 1536);

#pragma unroll 1
    for (int t = 0; t < 9; ++t) {
        // ---- prefetch tap t+1 (issue loads before consuming tap t) ----
        float n00 = 0.f, n01 = 0.f, n10 = 0.f, n11 = 0.f;
        u32x4 m00, m01, m10, m11;
        bf16x8 nf0, nf1, nf2, nf3;
        if (t < 8) {
            const short *r00, *r01, *r10, *r11;
            GEOM(t + 1, n00, n01, n10, n11, r00, r01, r10, r11);
            m00 = *(const u32x4*)r00;
            m01 = *(const u32x4*)r01;
            m10 = *(const u32x4*)r10;
            m11 = *(const u32x4*)r11;
            const short* wb = wtb + (size_t)(t + 1) * 4096;
            nf0 = *(const bf16x8*)(wb);
            nf1 = *(const bf16x8*)(wb + 512);
            nf2 = *(const bf16x8*)(wb + 1024);
            nf3 = *(const bf16x8*)(wb + 1536);
        }

        // ---- bilinear for tap t (bf16->f32 via bit ops, f32 blend) ----
        union { bf16x8 v; short s[8]; } pf;
#pragma unroll
        for (int wd = 0; wd < 4; ++wd) {
            const unsigned int u00 = v00[wd], u01 = v01[wd];
            const unsigned int u10 = v10[wd], u11 = v11[wd];
            float lo, hi;
            lo  = c00 * __builtin_bit_cast(float, u00 << 16);
            hi  = c00 * __builtin_bit_cast(float, u00 & 0xffff0000u);
            lo += c01 * __builtin_bit_cast(float, u01 << 16);
            hi += c01 * __builtin_bit_cast(float, u01 & 0xffff0000u);
            lo += c10 * __builtin_bit_cast(float, u10 << 16);
            hi += c10 * __builtin_bit_cast(float, u10 & 0xffff0000u);
            lo += c11 * __builtin_bit_cast(float, u11 << 16);
            hi += c11 * __builtin_bit_cast(float, u11 & 0xffff0000u);
            pf.s[2 * wd]     = f2bf(lo);
            pf.s[2 * wd + 1] = f2bf(hi);
        }

        acc[0] = __builtin_amdgcn_mfma_f32_16x16x32_bf16(wf0, pf.v, acc[0], 0, 0, 0);
        acc[1] = __builtin_amdgcn_mfma_f32_16x16x32_bf16(wf1, pf.v, acc[1], 0, 0, 0);
        acc[2] = __builtin_amdgcn_mfma_f32_16x16x32_bf16(wf2, pf.v, acc[2], 0, 0, 0);
        acc[3] = __builtin_amdgcn_mfma_f32_16x16x32_bf16(wf3, pf.v, acc[3], 0, 0, 0);

        // ---- rotate pipeline ----
        v00 = m00; v01 = m01; v10 = m10; v11 = m11;
        wf0 = nf0; wf1 = nf1; wf2 = nf2; wf3 = nf3;
        c00 = n00; c01 = n01; c10 = n10; c11 = n11;
    }

    // ---- pair reduction: ks=1 -> LDS, ks=0 adds + stores ----
    __shared__ float red[2][64][17];     // stride 17: gcd(17,32)=1 -> free
    if (ks == 1) {
#pragma unroll
        for (int mt = 0; mt < 4; ++mt)
#pragma unroll
            for (int r = 0; r < 4; ++r)
                red[strip][lane][4 * mt + r] = acc[mt][r];
    }
    __syncthreads();
    if (ks == 0) {
        float* op = out + (size_t)b * COUT * HW + pix0 + px;
#pragma unroll
        for (int mt = 0; mt < 4; ++mt) {
            const f32x4 bv = *(const f32x4*)(bias + 16 * mt + 4 * g);
#pragma unroll
            for (int r = 0; r < 4; ++r) {
                const int o = 16 * mt + 4 * g + r;
                op[(size_t)o * HW] = acc[mt][r] + red[strip][lane][4 * mt + r] + bv[r];
            }
        }
    }
}

// ---------------------------------------------------------------------------
// Fallback (round-7 NCHW path) if ws_size can't hold the transposed input.
// ---------------------------------------------------------------------------
__global__ void wt2_kernel(const float* __restrict__ w, short* __restrict__ wt2) {
    int i = blockIdx.x * 256 + threadIdx.x;
    if (i < 9 * COUT * CIN) {
        int c = i & 63, o = (i >> 6) & 63, t = i >> 12;
        wt2[i] = f2bf(w[(o * CIN + c) * 9 + t]);
    }
}

__global__ __launch_bounds__(256) void pdconv_mfma_kernel(
    const float* __restrict__ in, const short* __restrict__ wt2,
    const float* __restrict__ rate_map, const float* __restrict__ bias,
    float* __restrict__ out)
{
    const int tid = threadIdx.x, wave = tid >> 6, lane = tid & 63;
    const int px = lane & 15, g = lane >> 4;
    const int cpx = gridDim.x >> 3;
    const int bid = (blockIdx.x & 7) * cpx + (blockIdx.x >> 3);
    const int base = bid * 64 + wave * 16;
    const int b = base / HW, pix0 = base - b * HW;
    const int y = pix0 / WW, x0 = pix0 - y * WW, x = x0 + px;
    const float rate = rate_map[base + px];
    const float fy = (float)y, fx = (float)x;
    f32x4 acc[4];
#pragma unroll
    for (int mt = 0; mt < 4; ++mt) acc[mt] = (f32x4){0.f, 0.f, 0.f, 0.f};
    const float* img  = in + (size_t)b * CIN * HW;
    const float* imgg = img + (size_t)g * 8 * HW;
#pragma unroll 1
    for (int t = 0; t < 9; ++t) {
        const int ky = t / 3, kx = t - 3 * ky;
        const float sy = fy + (float)(ky - 1) * rate;
        const float sx = fx + (float)(kx - 1) * rate;
        const float y0f = floorf(sy), x0f = floorf(sx);
        const float wy = sy - y0f, wx = sx - x0f;
        const int y0 = (int)y0f, x0i = (int)x0f, y1 = y0 + 1, x1 = x0i + 1;
        const float omwy = 1.0f - wy, omwx = 1.0f - wx;
        const float vy0 = (y0 >= 0 && y0 < HH) ? 1.0f : 0.0f;
        const float vy1 = (y1 >= 0 && y1 < HH) ? 1.0f : 0.0f;
        const float vx0 = (x0i >= 0 && x0i < WW) ? 1.0f : 0.0f;
        const float vx1 = (x1 >= 0 && x1 < WW) ? 1.0f : 0.0f;
        const float c00 = omwy * omwx * vy0 * vx0, c01 = omwy * wx * vy0 * vx1;
        const float c10 = wy * omwx * vy1 * vx0,  c11 = wy * wx * vy1 * vx1;
        const int cy0 = min(max(y0, 0), HH - 1), cy1 = min(max(y1, 0), HH - 1);
        const int cx0 = min(max(x0i, 0), WW - 1), cx1 = min(max(x1, 0), WW - 1);
        const int i00 = cy0 * WW + cx0, i01 = cy0 * WW + cx1;
        const int i10 = cy1 * WW + cx0, i11 = cy1 * WW + cx1;
#pragma unroll
        for (int ks = 0; ks < 2; ++ks) {
            bf16x8 wf[4];
#pragma unroll
            for (int mt = 0; mt < 4; ++mt)
                wf[mt] = *(const bf16x8*)(wt2 +
                          ((t * COUT + 16 * mt + px) * CIN + 32 * ks + 8 * g));
            float a[8];
#pragma unroll
            for (int j = 0; j < 8; ++j) {
                const float* ch = imgg + (size_t)(32 * ks + j) * HW;
                a[j] = c00 * ch[i00] + c01 * ch[i01] + c10 * ch[i10] + c11 * ch[i11];
            }
            union { bf16x8 v; short s[8]; } pf;
#pragma unroll
            for (int j = 0; j < 8; ++j) pf.s[j] = f2bf(a[j]);
#pragma unroll
            for (int mt = 0; mt < 4; ++mt)
                acc[mt] = __builtin_amdgcn_mfma_f32_16x16x32_bf16(
                              wf[mt], pf.v, acc[mt], 0, 0, 0);
        }
    }
    float* op = out + (size_t)b * COUT * HW + pix0 + px;
#pragma unroll
    for (int mt = 0; mt < 4; ++mt)
#pragma unroll
        for (int r = 0; r < 4; ++r) {
            const int o = 16 * mt + 4 * g + r;
            op[(size_t)o * HW] = acc[mt][r] + bias[o];
        }
}

extern "C" void kernel_launch(void* const* d_in, const int* in_sizes, int n_in,
                              void* d_out, int out_size, void* d_ws, size_t ws_size,
                              hipStream_t stream) {
    (void)in_sizes; (void)n_in; (void)out_size;
    const float* in   = (const float*)d_in[0];
    const float* w    = (const float*)d_in[1];
    const float* rm   = (const float*)d_in[2];
    const float* bias = (const float*)d_in[3];
    float* out = (float*)d_out;

    const size_t WTF_BYTES = 36864 * sizeof(short);                 // 73,728
    const size_t TIN_BYTES = (size_t)NB * HW * CIN * sizeof(short); // 13,107,200

    if (ws_size >= WTF_BYTES + TIN_BYTES) {
        short* wtf = (short*)d_ws;
        short* tin = (short*)((char*)d_ws + WTF_BYTES);
        hipLaunchKernelGGL(wtf_kernel, dim3(144), dim3(256), 0, stream, w, wtf);
        hipLaunchKernelGGL(tin_kernel, dim3((NB * HW + 255) / 256), dim3(256),
                           0, stream, in, tin);
        const int nblocks = (NB * HW) / 32;   // 3200: 2 strips / block
        hipLaunchKernelGGL(pdconv_split_kernel, dim3(nblocks), dim3(256), 0,
                           stream, tin, wtf, rm, bias, out);
    } else {
        short* wt2 = (short*)d_ws;   // 73,728 B
        hipLaunchKernelGGL(wt2_kernel, dim3(144), dim3(256), 0, stream, w, wt2);
        const int nblocks = (NB * HW) / 64;   // 1600
        hipLaunchKernelGGL(pdconv_mfma_kernel, dim3(nblocks), dim3(256), 0,
                           stream, in, wt2, rm, bias, out);
    }
}